// Round 14
// baseline (310.843 us; speedup 1.0000x reference)
//
#include <hip/hip_runtime.h>

#define B_ 2
#define T_ 4096
#define D_ 256
#define H_ 8
#define DK_ 32
#define EPS_ 1e-5f

typedef __attribute__((ext_vector_type(8))) __bf16 bf16x8;
typedef __attribute__((ext_vector_type(4))) float f32x4;

// 1/sqrt(32) * log2(e): folded into Q so softmax uses raw v_exp_f32 (2^x)
#define QSCALE 0.25503497f

__device__ inline unsigned short f2bf(float f) {
  unsigned int u = __float_as_uint(f);
  unsigned int r = (u + 0x7fffu + ((u >> 16) & 1u)) >> 16;  // RNE
  return (unsigned short)r;
}

__device__ inline f32x4 mfma16(bf16x8 a, bf16x8 b, f32x4 c) {
  return __builtin_amdgcn_mfma_f32_16x16x32_bf16(a, b, c, 0, 0, 0);
}

// ---- prep: fold BN into depthwise conv weights/bias ----
__global__ void prep_bn(const float* __restrict__ dw_w, const float* __restrict__ dw_b,
                        const float* __restrict__ gma, const float* __restrict__ bta,
                        const float* __restrict__ mu, const float* __restrict__ var,
                        float* __restrict__ wf, float* __restrict__ yb) {
  int i = blockIdx.x * blockDim.x + threadIdx.x;  // p*D + c, 768 total
  if (i >= 3 * D_) return;
  float s = gma[i] * rsqrtf(var[i] + EPS_);
  wf[i * 3 + 0] = dw_w[i * 3 + 0] * s;
  wf[i * 3 + 1] = dw_w[i * 3 + 1] * s;
  wf[i * 3 + 2] = dw_w[i * 3 + 2] * s;
  yb[i] = (dw_b[i] - mu[i]) * s + bta[i];
}

// ---- convert pointwise / output weights to bf16 ----
__global__ void cvt_w(const float* __restrict__ pw_w, const float* __restrict__ out_w,
                      unsigned short* __restrict__ Wb, unsigned short* __restrict__ Ob) {
  int i = blockIdx.x * blockDim.x + threadIdx.x;
  if (i < 3 * D_ * D_) Wb[i] = f2bf(pw_w[i]);
  if (i < D_ * D_) Ob[i] = f2bf(out_w[i]);
}

// ---- depthwise conv (K=3, pad same) + BN -> Y bf16 [3][B*T][D] ----
__global__ __launch_bounds__(256) void conv_bn(const float* __restrict__ x,
                                               const float* __restrict__ wf,
                                               const float* __restrict__ yb,
                                               unsigned short* __restrict__ Y) {
  int bt = blockIdx.x;        // b*T + t
  int c = threadIdx.x;        // 0..255
  int t = bt & (T_ - 1);
  const float* xp = x + (size_t)bt * D_ + c;
  float x0 = xp[0];
  float xm = (t > 0) ? xp[-D_] : 0.f;
  float xq = (t < T_ - 1) ? xp[D_] : 0.f;
#pragma unroll
  for (int p = 0; p < 3; ++p) {
    int pc = p * D_ + c;
    float y = fmaf(xm, wf[pc * 3 + 0],
              fmaf(x0, wf[pc * 3 + 1],
              fmaf(xq, wf[pc * 3 + 2], yb[pc])));
    Y[(size_t)p * (B_ * T_ * D_) + (size_t)bt * D_ + c] = f2bf(y);
  }
}

// ---- QKV pointwise GEMM: Z[p] = Y[p] (8192x256) * Wb[p]^T (256x256) + pw_b ----
// Q (pre-scaled) and K as [b][h][t][dk].
// V (p==2): swapped operands mfma(A=W, B=Y) -> C[o][t], so Vt[b][h][dk][t]
// stores are 32B-contiguous per 16-lane group.
__global__ __launch_bounds__(256) void qkv_gemm(const unsigned short* __restrict__ Y,
                                                const unsigned short* __restrict__ Wb,
                                                const float* __restrict__ pw_b,
                                                unsigned short* __restrict__ Q,
                                                unsigned short* __restrict__ Kk,
                                                unsigned short* __restrict__ Vt) {
  int p = blockIdx.y;
  int m0 = blockIdx.x * 16;
  int wv = threadIdx.x >> 6;
  int lane = threadIdx.x & 63;
  int lm = lane & 15, g = lane >> 4;
  int n0 = wv * 64;
  const unsigned short* Yp = Y + (size_t)p * (B_ * T_ * D_);
  const unsigned short* Wp = Wb + (size_t)p * (D_ * D_);
  f32x4 acc[4] = {};

  if (p < 2) {
    for (int k0 = 0; k0 < D_; k0 += 32) {
      bf16x8 a = *reinterpret_cast<const bf16x8*>(Yp + (size_t)(m0 + lm) * D_ + k0 + 8 * g);
#pragma unroll
      for (int j = 0; j < 4; ++j) {
        bf16x8 b = *reinterpret_cast<const bf16x8*>(Wp + (size_t)(n0 + j * 16 + lm) * D_ + k0 + 8 * g);
        acc[j] = mfma16(a, b, acc[j]);
      }
    }
    float scl = (p == 0) ? QSCALE : 1.0f;
#pragma unroll
    for (int j = 0; j < 4; ++j) {
      int o = n0 + j * 16 + lm;
      float bias = pw_b[p * D_ + o];
      int h = o >> 5, dk = o & 31;
#pragma unroll
      for (int r = 0; r < 4; ++r) {
        int row = m0 + g * 4 + r;  // b*T + t
        int b = row >> 12, t = row & (T_ - 1);
        unsigned short bv = f2bf((acc[j][r] + bias) * scl);
        size_t bh = (size_t)(b * H_ + h);
        if (p == 0)
          Q[(bh * T_ + t) * DK_ + dk] = bv;
        else
          Kk[(bh * T_ + t) * DK_ + dk] = bv;
      }
    }
  } else {
    // V path: A=W rows (o), B=Y rows (t) -> C[row=o local 4g+r][col=t lm]
    for (int k0 = 0; k0 < D_; k0 += 32) {
      bf16x8 by = *reinterpret_cast<const bf16x8*>(Yp + (size_t)(m0 + lm) * D_ + k0 + 8 * g);
#pragma unroll
      for (int j = 0; j < 4; ++j) {
        bf16x8 aw = *reinterpret_cast<const bf16x8*>(Wp + (size_t)(n0 + j * 16 + lm) * D_ + k0 + 8 * g);
        acc[j] = mfma16(aw, by, acc[j]);
      }
    }
    int row = m0 + lm;  // b*T + t
    int b = row >> 12, t = row & (T_ - 1);
#pragma unroll
    for (int j = 0; j < 4; ++j) {
#pragma unroll
      for (int r = 0; r < 4; ++r) {
        int o = n0 + j * 16 + 4 * g + r;
        int h = o >> 5, dk = o & 31;
        unsigned short bv = f2bf(acc[j][r] + pw_b[2 * D_ + o]);
        Vt[((size_t)(b * H_ + h) * DK_ + dk) * T_ + t] = bv;
      }
    }
  }
}

// ---- flash attention, SPLIT-K: each wave does HALF the key range ----
// Grid doubles (8192 waves) -> 32 waves/CU, twice the latency-hiding TLP
// (round-13 showed grid-capped occupancy 39% with VGPR=52 permitting 8 w/SIMD;
// register prefetch was WAR-defeated, so we buy TLP instead of ILP).
// Outputs unnormalized partials O (f32) + per-row (m, l); merge kernel combines.
__global__ __launch_bounds__(256) void attn_part(const unsigned short* __restrict__ Q,
                                                 const unsigned short* __restrict__ Kk,
                                                 const unsigned short* __restrict__ Vt,
                                                 float* __restrict__ Opart,
                                                 float* __restrict__ Ml) {
  int wv = threadIdx.x >> 6, lane = threadIdx.x & 63;
  int lm = lane & 15, g = lane >> 4;
  int wid = blockIdx.x * 4 + wv;  // 0..8191
  int bh = wid >> 9;              // b*H + h (512 waves per head)
  int qt = (wid >> 1) & 255;
  int half = wid & 1;
  int q0 = qt * 16;
  const unsigned short* Qh = Q + (size_t)bh * (T_ * DK_);
  const unsigned short* Kh = Kk + (size_t)bh * (T_ * DK_);
  const unsigned short* Vh = Vt + (size_t)bh * (DK_ * T_);

  bf16x8 qf = *reinterpret_cast<const bf16x8*>(Qh + (size_t)(q0 + lm) * DK_ + 8 * g);

  const int ra = 8 * (lm >> 2) + (lm & 3);  // permuted K row for score A-frag
  const unsigned short* Kp = Kh + (size_t)ra * DK_ + 8 * g;
  const unsigned short* Vp = Vh + (size_t)lm * T_ + 8 * g;

  bf16x8 one8;
#pragma unroll
  for (int i = 0; i < 8; ++i) one8[i] = (__bf16)1.0f;

  float mrow = -1e30f;
  f32x4 lacc = {};
  f32x4 acc_lo = {}, acc_hi = {};

  const int kbeg = half * (T_ / 2);
  const int kend = kbeg + (T_ / 2);

  for (int k0 = kbeg; k0 < kend; k0 += 64) {
    bf16x8 kA0 = *reinterpret_cast<const bf16x8*>(Kp + (size_t)k0 * DK_);
    bf16x8 kA1 = *reinterpret_cast<const bf16x8*>(Kp + (size_t)(k0 + 4) * DK_);
    bf16x8 kB0 = *reinterpret_cast<const bf16x8*>(Kp + (size_t)(k0 + 32) * DK_);
    bf16x8 kB1 = *reinterpret_cast<const bf16x8*>(Kp + (size_t)(k0 + 36) * DK_);
    bf16x8 v00 = *reinterpret_cast<const bf16x8*>(Vp + k0);
    bf16x8 v10 = *reinterpret_cast<const bf16x8*>(Vp + k0 + 32);
    bf16x8 v01 = *reinterpret_cast<const bf16x8*>(Vp + 16 * T_ + k0);
    bf16x8 v11 = *reinterpret_cast<const bf16x8*>(Vp + 16 * T_ + k0 + 32);

    f32x4 z = {};
    f32x4 sA0 = mfma16(kA0, qf, z);  // keys k0+8g+r
    f32x4 sA1 = mfma16(kA1, qf, z);  // keys k0+8g+4+r
    f32x4 sB0 = mfma16(kB0, qf, z);  // keys k0+32+8g+r
    f32x4 sB1 = mfma16(kB1, qf, z);  // keys k0+32+8g+4+r

    float mx = fmaxf(
        fmaxf(fmaxf(fmaxf(sA0[0], sA0[1]), fmaxf(sA0[2], sA0[3])),
              fmaxf(fmaxf(sA1[0], sA1[1]), fmaxf(sA1[2], sA1[3]))),
        fmaxf(fmaxf(fmaxf(sB0[0], sB0[1]), fmaxf(sB0[2], sB0[3])),
              fmaxf(fmaxf(sB1[0], sB1[1]), fmaxf(sB1[2], sB1[3]))));
    mx = fmaxf(mx, __shfl_xor(mx, 16));
    mx = fmaxf(mx, __shfl_xor(mx, 32));

    // defer-max (T13): only rescale when the row max grew by >8 (log2 units)
    if (!__all(mx <= mrow + 8.f)) {
      float mn = fmaxf(mrow, mx);
      float al = __builtin_amdgcn_exp2f(mrow - mn);
      mrow = mn;
      float al0 = __shfl(al, 4 * g + 0);
      float al1 = __shfl(al, 4 * g + 1);
      float al2 = __shfl(al, 4 * g + 2);
      float al3 = __shfl(al, 4 * g + 3);
      lacc[0] *= al0; acc_lo[0] *= al0; acc_hi[0] *= al0;
      lacc[1] *= al1; acc_lo[1] *= al1; acc_hi[1] *= al1;
      lacc[2] *= al2; acc_lo[2] *= al2; acc_hi[2] *= al2;
      lacc[3] *= al3; acc_lo[3] *= al3; acc_hi[3] *= al3;
    }

    bf16x8 pfA, pfB;
    pfA[0] = (__bf16)__builtin_amdgcn_exp2f(sA0[0] - mrow);
    pfA[1] = (__bf16)__builtin_amdgcn_exp2f(sA0[1] - mrow);
    pfA[2] = (__bf16)__builtin_amdgcn_exp2f(sA0[2] - mrow);
    pfA[3] = (__bf16)__builtin_amdgcn_exp2f(sA0[3] - mrow);
    pfA[4] = (__bf16)__builtin_amdgcn_exp2f(sA1[0] - mrow);
    pfA[5] = (__bf16)__builtin_amdgcn_exp2f(sA1[1] - mrow);
    pfA[6] = (__bf16)__builtin_amdgcn_exp2f(sA1[2] - mrow);
    pfA[7] = (__bf16)__builtin_amdgcn_exp2f(sA1[3] - mrow);
    pfB[0] = (__bf16)__builtin_amdgcn_exp2f(sB0[0] - mrow);
    pfB[1] = (__bf16)__builtin_amdgcn_exp2f(sB0[1] - mrow);
    pfB[2] = (__bf16)__builtin_amdgcn_exp2f(sB0[2] - mrow);
    pfB[3] = (__bf16)__builtin_amdgcn_exp2f(sB0[3] - mrow);
    pfB[4] = (__bf16)__builtin_amdgcn_exp2f(sB1[0] - mrow);
    pfB[5] = (__bf16)__builtin_amdgcn_exp2f(sB1[1] - mrow);
    pfB[6] = (__bf16)__builtin_amdgcn_exp2f(sB1[2] - mrow);
    pfB[7] = (__bf16)__builtin_amdgcn_exp2f(sB1[3] - mrow);

    // l via MFMA: lacc[r] += sum_k P[q=4g+r][k]  (replicated over lm)
    lacc = mfma16(pfA, one8, lacc);
    lacc = mfma16(pfB, one8, lacc);

    acc_lo = mfma16(pfA, v00, acc_lo);
    acc_lo = mfma16(pfB, v10, acc_lo);
    acc_hi = mfma16(pfA, v01, acc_hi);
    acc_hi = mfma16(pfB, v11, acc_hi);
  }

  // partial epilogue: unnormalized O (f32) + per-row m, l
  size_t hb = (size_t)(half * 16 + bh);
#pragma unroll
  for (int r = 0; r < 4; ++r) {
    int q = q0 + 4 * g + r;
    size_t base = (hb * T_ + q) * DK_;
    Opart[base + lm] = acc_lo[r];
    Opart[base + 16 + lm] = acc_hi[r];
  }
  if (g == 0) Ml[(hb * T_ + q0 + lm) * 2 + 0] = mrow;       // m for q=q0+lm
  if (lm == 0) {
#pragma unroll
    for (int r = 0; r < 4; ++r)
      Ml[(hb * T_ + q0 + 4 * g + r) * 2 + 1] = lacc[r];     // l for q=q0+4g+r
  }
}

// ---- merge the two K-halves: ctx = (O0*2^(m0-M) + O1*2^(m1-M)) / (l0*2^.. + l1*2^..) ----
__global__ __launch_bounds__(256) void attn_merge(const float* __restrict__ Opart,
                                                  const float* __restrict__ Ml,
                                                  unsigned short* __restrict__ ctx) {
  int tid = blockIdx.x * 256 + threadIdx.x;  // over 16*4096*32
  int dk = tid & 31;
  int rowid = tid >> 5;        // bh*T + q
  int bh = rowid >> 12;
  int q = rowid & (T_ - 1);
  size_t r0 = (size_t)bh * T_ + q;
  size_t r1 = (size_t)(16 + bh) * T_ + q;
  float m0 = Ml[r0 * 2 + 0], l0 = Ml[r0 * 2 + 1];
  float m1 = Ml[r1 * 2 + 0], l1 = Ml[r1 * 2 + 1];
  float M = fmaxf(m0, m1);
  float s0 = __builtin_amdgcn_exp2f(m0 - M);
  float s1 = __builtin_amdgcn_exp2f(m1 - M);
  float a0 = Opart[r0 * DK_ + dk];
  float a1 = Opart[r1 * DK_ + dk];
  float val = (a0 * s0 + a1 * s1) / (l0 * s0 + l1 * s1);
  int b = bh >> 3, h = bh & 7;
  ctx[((size_t)(b * T_ + q)) * D_ + h * DK_ + dk] = f2bf(val);
}

// ---- output projection: out = ctx (8192x256) * Ob^T (256x256) + out_b, f32 out ----
__global__ __launch_bounds__(256) void out_gemm(const unsigned short* __restrict__ ctx,
                                                const unsigned short* __restrict__ Ob,
                                                const float* __restrict__ out_b,
                                                float* __restrict__ out) {
  int m0 = blockIdx.x * 16;
  int wv = threadIdx.x >> 6, lane = threadIdx.x & 63;
  int lm = lane & 15, g = lane >> 4;
  int n0 = wv * 64;
  f32x4 acc[4] = {};
  for (int k0 = 0; k0 < D_; k0 += 32) {
    bf16x8 a = *reinterpret_cast<const bf16x8*>(ctx + (size_t)(m0 + lm) * D_ + k0 + 8 * g);
#pragma unroll
    for (int j = 0; j < 4; ++j) {
      bf16x8 b = *reinterpret_cast<const bf16x8*>(Ob + (size_t)(n0 + j * 16 + lm) * D_ + k0 + 8 * g);
      acc[j] = mfma16(a, b, acc[j]);
    }
  }
#pragma unroll
  for (int j = 0; j < 4; ++j) {
    int o = n0 + j * 16 + lm;
    float bias = out_b[o];
#pragma unroll
    for (int r = 0; r < 4; ++r) {
      int row = m0 + g * 4 + r;
      out[(size_t)row * D_ + o] = acc[j][r] + bias;
    }
  }
}

extern "C" void kernel_launch(void* const* d_in, const int* in_sizes, int n_in,
                              void* d_out, int out_size, void* d_ws, size_t ws_size,
                              hipStream_t stream) {
  const float* x = (const float*)d_in[0];
  const float* dw_w = (const float*)d_in[1];
  const float* dw_b = (const float*)d_in[2];
  const float* gma = (const float*)d_in[3];
  const float* bta = (const float*)d_in[4];
  const float* mu = (const float*)d_in[5];
  const float* var = (const float*)d_in[6];
  const float* pw_w = (const float*)d_in[7];
  const float* pw_b = (const float*)d_in[8];
  const float* out_w = (const float*)d_in[9];
  const float* out_b = (const float*)d_in[10];
  float* out = (float*)d_out;

  char* ws = (char*)d_ws;
  size_t off = 0;
  auto alloc = [&](size_t bytes) -> void* {
    void* ptr = (void*)(ws + off);
    off += (bytes + 255) & ~(size_t)255;
    return ptr;
  };
  float* wf = (float*)alloc(3 * 256 * 3 * 4);
  float* yb = (float*)alloc(3 * 256 * 4);
  unsigned short* Wb = (unsigned short*)alloc((size_t)3 * 256 * 256 * 2);
  unsigned short* Ob = (unsigned short*)alloc((size_t)256 * 256 * 2);
  unsigned short* Y = (unsigned short*)alloc((size_t)3 * 8192 * 256 * 2);
  unsigned short* Q = (unsigned short*)alloc((size_t)16 * 4096 * 32 * 2);
  unsigned short* Kk = (unsigned short*)alloc((size_t)16 * 4096 * 32 * 2);
  unsigned short* Vt = (unsigned short*)alloc((size_t)16 * 32 * 4096 * 2);
  unsigned short* ctx = (unsigned short*)alloc((size_t)8192 * 256 * 2);
  float* Opart = (float*)alloc((size_t)2 * 16 * 4096 * 32 * 4);  // 16 MB
  float* Ml = (float*)alloc((size_t)2 * 16 * 4096 * 2 * 4);      // 1 MB

  hipLaunchKernelGGL(prep_bn, dim3(3), dim3(256), 0, stream, dw_w, dw_b, gma, bta, mu, var, wf, yb);
  hipLaunchKernelGGL(cvt_w, dim3(768), dim3(256), 0, stream, pw_w, out_w, Wb, Ob);
  hipLaunchKernelGGL(conv_bn, dim3(8192), dim3(256), 0, stream, x, wf, yb, Y);
  hipLaunchKernelGGL(qkv_gemm, dim3(512, 3), dim3(256), 0, stream, Y, Wb, pw_b, Q, Kk, Vt);
  hipLaunchKernelGGL(attn_part, dim3(2048), dim3(256), 0, stream, Q, Kk, Vt, Opart, Ml);
  hipLaunchKernelGGL(attn_merge, dim3(8192), dim3(256), 0, stream, Opart, Ml, ctx);
  hipLaunchKernelGGL(out_gemm, dim3(512), dim3(256), 0, stream, ctx, Ob, out_b, out);
}

// Round 16
// 206.498 us; speedup vs baseline: 1.5053x; 1.5053x over previous
//
#include <hip/hip_runtime.h>

#define B_ 2
#define T_ 4096
#define D_ 256
#define H_ 8
#define DK_ 32
#define EPS_ 1e-5f

typedef __attribute__((ext_vector_type(8))) __bf16 bf16x8;
typedef __attribute__((ext_vector_type(4))) float f32x4;

// 1/sqrt(32) * log2(e): folded into Q so softmax uses raw v_exp_f32 (2^x)
#define QSCALE 0.25503497f

__device__ inline unsigned short f2bf(float f) {
  unsigned int u = __float_as_uint(f);
  unsigned int r = (u + 0x7fffu + ((u >> 16) & 1u)) >> 16;  // RNE
  return (unsigned short)r;
}

__device__ inline f32x4 mfma16(bf16x8 a, bf16x8 b, f32x4 c) {
  return __builtin_amdgcn_mfma_f32_16x16x32_bf16(a, b, c, 0, 0, 0);
}

// async global->LDS, 16B per lane; LDS dest = uniform base + lane*16 (HW rule)
__device__ inline void gload16(const unsigned short* g, unsigned short* l) {
  __builtin_amdgcn_global_load_lds(
      (const __attribute__((address_space(1))) void*)g,
      (__attribute__((address_space(3))) void*)l, 16, 0, 0);
}

// ---- prep: fold BN into depthwise conv weights/bias ----
__global__ void prep_bn(const float* __restrict__ dw_w, const float* __restrict__ dw_b,
                        const float* __restrict__ gma, const float* __restrict__ bta,
                        const float* __restrict__ mu, const float* __restrict__ var,
                        float* __restrict__ wf, float* __restrict__ yb) {
  int i = blockIdx.x * blockDim.x + threadIdx.x;  // p*D + c, 768 total
  if (i >= 3 * D_) return;
  float s = gma[i] * rsqrtf(var[i] + EPS_);
  wf[i * 3 + 0] = dw_w[i * 3 + 0] * s;
  wf[i * 3 + 1] = dw_w[i * 3 + 1] * s;
  wf[i * 3 + 2] = dw_w[i * 3 + 2] * s;
  yb[i] = (dw_b[i] - mu[i]) * s + bta[i];
}

// ---- convert pointwise / output weights to bf16 ----
__global__ void cvt_w(const float* __restrict__ pw_w, const float* __restrict__ out_w,
                      unsigned short* __restrict__ Wb, unsigned short* __restrict__ Ob) {
  int i = blockIdx.x * blockDim.x + threadIdx.x;
  if (i < 3 * D_ * D_) Wb[i] = f2bf(pw_w[i]);
  if (i < D_ * D_) Ob[i] = f2bf(out_w[i]);
}

// ---- depthwise conv (K=3, pad same) + BN -> Y bf16 [3][B*T][D] ----
__global__ __launch_bounds__(256) void conv_bn(const float* __restrict__ x,
                                               const float* __restrict__ wf,
                                               const float* __restrict__ yb,
                                               unsigned short* __restrict__ Y) {
  int bt = blockIdx.x;        // b*T + t
  int c = threadIdx.x;        // 0..255
  int t = bt & (T_ - 1);
  const float* xp = x + (size_t)bt * D_ + c;
  float x0 = xp[0];
  float xm = (t > 0) ? xp[-D_] : 0.f;
  float xq = (t < T_ - 1) ? xp[D_] : 0.f;
#pragma unroll
  for (int p = 0; p < 3; ++p) {
    int pc = p * D_ + c;
    float y = fmaf(xm, wf[pc * 3 + 0],
              fmaf(x0, wf[pc * 3 + 1],
              fmaf(xq, wf[pc * 3 + 2], yb[pc])));
    Y[(size_t)p * (B_ * T_ * D_) + (size_t)bt * D_ + c] = f2bf(y);
  }
}

// ---- QKV pointwise GEMM: Z[p] = Y[p] (8192x256) * Wb[p]^T (256x256) + pw_b ----
__global__ __launch_bounds__(256) void qkv_gemm(const unsigned short* __restrict__ Y,
                                                const unsigned short* __restrict__ Wb,
                                                const float* __restrict__ pw_b,
                                                unsigned short* __restrict__ Q,
                                                unsigned short* __restrict__ Kk,
                                                unsigned short* __restrict__ Vt) {
  int p = blockIdx.y;
  int m0 = blockIdx.x * 16;
  int wv = threadIdx.x >> 6;
  int lane = threadIdx.x & 63;
  int lm = lane & 15, g = lane >> 4;
  int n0 = wv * 64;
  const unsigned short* Yp = Y + (size_t)p * (B_ * T_ * D_);
  const unsigned short* Wp = Wb + (size_t)p * (D_ * D_);
  f32x4 acc[4] = {};

  if (p < 2) {
    for (int k0 = 0; k0 < D_; k0 += 32) {
      bf16x8 a = *reinterpret_cast<const bf16x8*>(Yp + (size_t)(m0 + lm) * D_ + k0 + 8 * g);
#pragma unroll
      for (int j = 0; j < 4; ++j) {
        bf16x8 b = *reinterpret_cast<const bf16x8*>(Wp + (size_t)(n0 + j * 16 + lm) * D_ + k0 + 8 * g);
        acc[j] = mfma16(a, b, acc[j]);
      }
    }
    float scl = (p == 0) ? QSCALE : 1.0f;
#pragma unroll
    for (int j = 0; j < 4; ++j) {
      int o = n0 + j * 16 + lm;
      float bias = pw_b[p * D_ + o];
      int h = o >> 5, dk = o & 31;
#pragma unroll
      for (int r = 0; r < 4; ++r) {
        int row = m0 + g * 4 + r;  // b*T + t
        int b = row >> 12, t = row & (T_ - 1);
        unsigned short bv = f2bf((acc[j][r] + bias) * scl);
        size_t bh = (size_t)(b * H_ + h);
        if (p == 0)
          Q[(bh * T_ + t) * DK_ + dk] = bv;
        else
          Kk[(bh * T_ + t) * DK_ + dk] = bv;
      }
    }
  } else {
    // V path: A=W rows (o), B=Y rows (t) -> C[row=o local 4g+r][col=t lm]
    for (int k0 = 0; k0 < D_; k0 += 32) {
      bf16x8 by = *reinterpret_cast<const bf16x8*>(Yp + (size_t)(m0 + lm) * D_ + k0 + 8 * g);
#pragma unroll
      for (int j = 0; j < 4; ++j) {
        bf16x8 aw = *reinterpret_cast<const bf16x8*>(Wp + (size_t)(n0 + j * 16 + lm) * D_ + k0 + 8 * g);
        acc[j] = mfma16(aw, by, acc[j]);
      }
    }
    int row = m0 + lm;  // b*T + t
    int b = row >> 12, t = row & (T_ - 1);
#pragma unroll
    for (int j = 0; j < 4; ++j) {
#pragma unroll
      for (int r = 0; r < 4; ++r) {
        int o = n0 + j * 16 + 4 * g + r;
        int h = o >> 5, dk = o & 31;
        unsigned short bv = f2bf(acc[j][r] + pw_b[2 * D_ + o]);
        Vt[((size_t)(b * H_ + h) * DK_ + dk) * T_ + t] = bv;
      }
    }
  }
}

// ---- flash attention with LDS-staged K/V tiles ----
// Round-14 showed duration invariant to ILP and TLP at ~38% issue-busy: the
// per-CU vector-memory address path is saturated by scattered wave loads
// (consecutive lanes in different 64B lines). Fix: stage K/V per 64-key tile
// into LDS via global_load_lds (coalesced by construction), shared by the
// block's 4 waves (same head) -> 4x fewer global requests, scatter moved to
// the LDS pipe with XOR swizzles making reads ~2-way (free, m136).
// K tile swizzle: col ^= ((row>>1)^(row>>3))&3  (16B units, 4 slots/row)
// V tile swizzle: col ^= row&7                  (16B units, 8 slots/row)
// Applied on the GLOBAL SOURCE (per-lane) with linear LDS dest (m104/m173),
// and identically on the ds_read side (rule #21).
__global__ __launch_bounds__(256) void attn(const unsigned short* __restrict__ Q,
                                            const unsigned short* __restrict__ Kk,
                                            const unsigned short* __restrict__ Vt,
                                            unsigned short* __restrict__ ctx) {
  __shared__ __align__(16) unsigned short Kt[2][2048];  // 64 rows x 32 (4KB) x2
  __shared__ __align__(16) unsigned short Vl[2][2048];  // 32 rows x 64 (4KB) x2
  int wv = threadIdx.x >> 6, lane = threadIdx.x & 63;
  int lm = lane & 15, g = lane >> 4;
  int wid = blockIdx.x * 4 + wv;  // 0..4095
  int bh = wid >> 8;              // b*H + h  (4 waves/block share this head)
  int qt = wid & 255;
  int q0 = qt * 16;
  const unsigned short* Qh = Q + (size_t)bh * (T_ * DK_);
  const unsigned short* Kh = Kk + (size_t)bh * (T_ * DK_);
  const unsigned short* Vh = Vt + (size_t)bh * (DK_ * T_);

  bf16x8 qf = *reinterpret_cast<const bf16x8*>(Qh + (size_t)(q0 + lm) * DK_ + 8 * g);

  const int ra = 8 * (lm >> 2) + (lm & 3);  // permuted K row for score A-frag

  // ---- staging descriptors: wave wv stages chunks 2wv, 2wv+1 (1KB each) ----
  // chunks 0..3 = K rows 16t..16t+15 ; chunks 4..7 = V rows 8(t-4)..+7
  int isK0, isK1, lds0, lds1;
  size_t src0, src1;
  {
    int t = 2 * wv;
    if (t < 4) {
      int row = 16 * t + (lane >> 2);
      int col = (lane & 3) ^ (((row >> 1) ^ (row >> 3)) & 3);
      isK0 = 1; src0 = (size_t)row * DK_ + col * 8; lds0 = t * 512;
    } else {
      int j = t - 4;
      int row = 8 * j + (lane >> 3);
      int col = (lane & 7) ^ (row & 7);
      isK0 = 0; src0 = (size_t)row * T_ + col * 8; lds0 = j * 512;
    }
    t = 2 * wv + 1;
    if (t < 4) {
      int row = 16 * t + (lane >> 2);
      int col = (lane & 3) ^ (((row >> 1) ^ (row >> 3)) & 3);
      isK1 = 1; src1 = (size_t)row * DK_ + col * 8; lds1 = t * 512;
    } else {
      int j = t - 4;
      int row = 8 * j + (lane >> 3);
      int col = (lane & 7) ^ (row & 7);
      isK1 = 0; src1 = (size_t)row * T_ + col * 8; lds1 = j * 512;
    }
  }

  // ---- LDS read offsets (loop-invariant, swizzled) ----
  auto fk = [](int r) { return ((r >> 1) ^ (r >> 3)) & 3; };
  const int oA0 = (ra + 0) * 32 + (g ^ fk(ra + 0)) * 8;
  const int oA1 = (ra + 4) * 32 + (g ^ fk(ra + 4)) * 8;
  const int oB0 = (ra + 32) * 32 + (g ^ fk(ra + 32)) * 8;
  const int oB1 = (ra + 36) * 32 + (g ^ fk(ra + 36)) * 8;
  const int fv = lm & 7;
  const int ov00 = lm * 64 + ((g ^ fv) * 8);
  const int ov10 = lm * 64 + (((4 + g) ^ fv) * 8);
  const int ov01 = (lm + 16) * 64 + ((g ^ fv) * 8);
  const int ov11 = (lm + 16) * 64 + (((4 + g) ^ fv) * 8);

  bf16x8 one8;
#pragma unroll
  for (int i = 0; i < 8; ++i) one8[i] = (__bf16)1.0f;

  float mrow = -1e30f;
  f32x4 lacc = {};
  f32x4 acc_lo = {}, acc_hi = {};

  // prologue: stage tile 0 into buf 0
  if (isK0) gload16(Kh + src0, &Kt[0][lds0]); else gload16(Vh + src0, &Vl[0][lds0]);
  if (isK1) gload16(Kh + src1, &Kt[0][lds1]); else gload16(Vh + src1, &Vl[0][lds1]);
  __syncthreads();

  int buf = 0;
  for (int k0 = 0; k0 < T_; k0 += 64) {
    // stage next tile into the other buffer (overlaps with compute below)
    if (k0 + 64 < T_) {
      int nb = buf ^ 1;
      int kn = k0 + 64;
      if (isK0) gload16(Kh + (size_t)kn * DK_ + src0, &Kt[nb][lds0]);
      else      gload16(Vh + kn + src0, &Vl[nb][lds0]);
      if (isK1) gload16(Kh + (size_t)kn * DK_ + src1, &Kt[nb][lds1]);
      else      gload16(Vh + kn + src1, &Vl[nb][lds1]);
    }

    const unsigned short* Kb = Kt[buf];
    const unsigned short* Vb = Vl[buf];
    bf16x8 kA0 = *reinterpret_cast<const bf16x8*>(Kb + oA0);
    bf16x8 kA1 = *reinterpret_cast<const bf16x8*>(Kb + oA1);
    bf16x8 kB0 = *reinterpret_cast<const bf16x8*>(Kb + oB0);
    bf16x8 kB1 = *reinterpret_cast<const bf16x8*>(Kb + oB1);
    bf16x8 v00 = *reinterpret_cast<const bf16x8*>(Vb + ov00);
    bf16x8 v10 = *reinterpret_cast<const bf16x8*>(Vb + ov10);
    bf16x8 v01 = *reinterpret_cast<const bf16x8*>(Vb + ov01);
    bf16x8 v11 = *reinterpret_cast<const bf16x8*>(Vb + ov11);

    f32x4 z = {};
    f32x4 sA0 = mfma16(kA0, qf, z);  // keys k0+8g+r
    f32x4 sA1 = mfma16(kA1, qf, z);  // keys k0+8g+4+r
    f32x4 sB0 = mfma16(kB0, qf, z);  // keys k0+32+8g+r
    f32x4 sB1 = mfma16(kB1, qf, z);  // keys k0+32+8g+4+r

    float mx = fmaxf(
        fmaxf(fmaxf(fmaxf(sA0[0], sA0[1]), fmaxf(sA0[2], sA0[3])),
              fmaxf(fmaxf(sA1[0], sA1[1]), fmaxf(sA1[2], sA1[3]))),
        fmaxf(fmaxf(fmaxf(sB0[0], sB0[1]), fmaxf(sB0[2], sB0[3])),
              fmaxf(fmaxf(sB1[0], sB1[1]), fmaxf(sB1[2], sB1[3]))));
    mx = fmaxf(mx, __shfl_xor(mx, 16));
    mx = fmaxf(mx, __shfl_xor(mx, 32));

    // defer-max (T13): only rescale when the row max grew by >8 (log2 units)
    if (!__all(mx <= mrow + 8.f)) {
      float mn = fmaxf(mrow, mx);
      float al = __builtin_amdgcn_exp2f(mrow - mn);
      mrow = mn;
      float al0 = __shfl(al, 4 * g + 0);
      float al1 = __shfl(al, 4 * g + 1);
      float al2 = __shfl(al, 4 * g + 2);
      float al3 = __shfl(al, 4 * g + 3);
      lacc[0] *= al0; acc_lo[0] *= al0; acc_hi[0] *= al0;
      lacc[1] *= al1; acc_lo[1] *= al1; acc_hi[1] *= al1;
      lacc[2] *= al2; acc_lo[2] *= al2; acc_hi[2] *= al2;
      lacc[3] *= al3; acc_lo[3] *= al3; acc_hi[3] *= al3;
    }

    bf16x8 pfA, pfB;
    pfA[0] = (__bf16)__builtin_amdgcn_exp2f(sA0[0] - mrow);
    pfA[1] = (__bf16)__builtin_amdgcn_exp2f(sA0[1] - mrow);
    pfA[2] = (__bf16)__builtin_amdgcn_exp2f(sA0[2] - mrow);
    pfA[3] = (__bf16)__builtin_amdgcn_exp2f(sA0[3] - mrow);
    pfA[4] = (__bf16)__builtin_amdgcn_exp2f(sA1[0] - mrow);
    pfA[5] = (__bf16)__builtin_amdgcn_exp2f(sA1[1] - mrow);
    pfA[6] = (__bf16)__builtin_amdgcn_exp2f(sA1[2] - mrow);
    pfA[7] = (__bf16)__builtin_amdgcn_exp2f(sA1[3] - mrow);
    pfB[0] = (__bf16)__builtin_amdgcn_exp2f(sB0[0] - mrow);
    pfB[1] = (__bf16)__builtin_amdgcn_exp2f(sB0[1] - mrow);
    pfB[2] = (__bf16)__builtin_amdgcn_exp2f(sB0[2] - mrow);
    pfB[3] = (__bf16)__builtin_amdgcn_exp2f(sB0[3] - mrow);
    pfB[4] = (__bf16)__builtin_amdgcn_exp2f(sB1[0] - mrow);
    pfB[5] = (__bf16)__builtin_amdgcn_exp2f(sB1[1] - mrow);
    pfB[6] = (__bf16)__builtin_amdgcn_exp2f(sB1[2] - mrow);
    pfB[7] = (__bf16)__builtin_amdgcn_exp2f(sB1[3] - mrow);

    // l via MFMA: lacc[r] += sum_k P[q=4g+r][k]  (replicated over lm)
    lacc = mfma16(pfA, one8, lacc);
    lacc = mfma16(pfB, one8, lacc);

    acc_lo = mfma16(pfA, v00, acc_lo);
    acc_lo = mfma16(pfB, v10, acc_lo);
    acc_hi = mfma16(pfA, v01, acc_hi);
    acc_hi = mfma16(pfB, v11, acc_hi);

    // next tile's staging must be complete and visible to all waves
    __syncthreads();
    buf ^= 1;
  }

  int b = bh >> 3, h = bh & 7;
  // lacc[r] = l for q = q0+4g+r  — exactly the acc row layout, no shuffles
  f32x4 inv;
#pragma unroll
  for (int r = 0; r < 4; ++r) inv[r] = 1.f / lacc[r];
  {
    int t = q0 + 4 * g;
    size_t base = ((size_t)(b * T_ + t)) * D_ + h * DK_;
    ctx[base + lm] = f2bf(acc_lo[0] * inv[0]);
    ctx[base + 16 + lm] = f2bf(acc_hi[0] * inv[0]);
    base += D_;
    ctx[base + lm] = f2bf(acc_lo[1] * inv[1]);
    ctx[base + 16 + lm] = f2bf(acc_hi[1] * inv[1]);
    base += D_;
    ctx[base + lm] = f2bf(acc_lo[2] * inv[2]);
    ctx[base + 16 + lm] = f2bf(acc_hi[2] * inv[2]);
    base += D_;
    ctx[base + lm] = f2bf(acc_lo[3] * inv[3]);
    ctx[base + 16 + lm] = f2bf(acc_hi[3] * inv[3]);
  }
}

// ---- output projection: out = ctx (8192x256) * Ob^T (256x256) + out_b, f32 out ----
__global__ __launch_bounds__(256) void out_gemm(const unsigned short* __restrict__ ctx,
                                                const unsigned short* __restrict__ Ob,
                                                const float* __restrict__ out_b,
                                                float* __restrict__ out) {
  int m0 = blockIdx.x * 16;
  int wv = threadIdx.x >> 6, lane = threadIdx.x & 63;
  int lm = lane & 15, g = lane >> 4;
  int n0 = wv * 64;
  f32x4 acc[4] = {};
  for (int k0 = 0; k0 < D_; k0 += 32) {
    bf16x8 a = *reinterpret_cast<const bf16x8*>(ctx + (size_t)(m0 + lm) * D_ + k0 + 8 * g);
#pragma unroll
    for (int j = 0; j < 4; ++j) {
      bf16x8 b = *reinterpret_cast<const bf16x8*>(Ob + (size_t)(n0 + j * 16 + lm) * D_ + k0 + 8 * g);
      acc[j] = mfma16(a, b, acc[j]);
    }
  }
#pragma unroll
  for (int j = 0; j < 4; ++j) {
    int o = n0 + j * 16 + lm;
    float bias = out_b[o];
#pragma unroll
    for (int r = 0; r < 4; ++r) {
      int row = m0 + g * 4 + r;
      out[(size_t)row * D_ + o] = acc[j][r] + bias;
    }
  }
}

extern "C" void kernel_launch(void* const* d_in, const int* in_sizes, int n_in,
                              void* d_out, int out_size, void* d_ws, size_t ws_size,
                              hipStream_t stream) {
  const float* x = (const float*)d_in[0];
  const float* dw_w = (const float*)d_in[1];
  const float* dw_b = (const float*)d_in[2];
  const float* gma = (const float*)d_in[3];
  const float* bta = (const float*)d_in[4];
  const float* mu = (const float*)d_in[5];
  const float* var = (const float*)d_in[6];
  const float* pw_w = (const float*)d_in[7];
  const float* pw_b = (const float*)d_in[8];
  const float* out_w = (const float*)d_in[9];
  const float* out_b = (const float*)d_in[10];
  float* out = (float*)d_out;

  char* ws = (char*)d_ws;
  size_t off = 0;
  auto alloc = [&](size_t bytes) -> void* {
    void* ptr = (void*)(ws + off);
    off += (bytes + 255) & ~(size_t)255;
    return ptr;
  };
  float* wf = (float*)alloc(3 * 256 * 3 * 4);
  float* yb = (float*)alloc(3 * 256 * 4);
  unsigned short* Wb = (unsigned short*)alloc((size_t)3 * 256 * 256 * 2);
  unsigned short* Ob = (unsigned short*)alloc((size_t)256 * 256 * 2);
  unsigned short* Y = (unsigned short*)alloc((size_t)3 * 8192 * 256 * 2);
  unsigned short* Q = (unsigned short*)alloc((size_t)16 * 4096 * 32 * 2);
  unsigned short* Kk = (unsigned short*)alloc((size_t)16 * 4096 * 32 * 2);
  unsigned short* Vt = (unsigned short*)alloc((size_t)16 * 32 * 4096 * 2);
  unsigned short* ctx = (unsigned short*)alloc((size_t)8192 * 256 * 2);

  hipLaunchKernelGGL(prep_bn, dim3(3), dim3(256), 0, stream, dw_w, dw_b, gma, bta, mu, var, wf, yb);
  hipLaunchKernelGGL(cvt_w, dim3(768), dim3(256), 0, stream, pw_w, out_w, Wb, Ob);
  hipLaunchKernelGGL(conv_bn, dim3(8192), dim3(256), 0, stream, x, wf, yb, Y);
  hipLaunchKernelGGL(qkv_gemm, dim3(512, 3), dim3(256), 0, stream, Y, Wb, pw_b, Q, Kk, Vt);
  hipLaunchKernelGGL(attn, dim3(1024), dim3(256), 0, stream, Q, Kk, Vt, ctx);
  hipLaunchKernelGGL(out_gemm, dim3(512), dim3(256), 0, stream, ctx, Ob, out_b, out);
}